// Round 5
// baseline (72.168 us; speedup 1.0000x reference)
//
#include <hip/hip_runtime.h>
#include <cstdint>
#include <cstddef>

// out[b,l] = min_d max(x[b,d], 1 - clip(w[l,d],0,1)),  B=1024, L=512, D=512, f32.
// Packed fp16 (v_pk_min/max_f16) tropical matmul, D packed into the fp16x2
// SIMD lanes (no transpose needed; both operands are d-major).
//
// Structure: split-D across BLOCKS for max occupancy.
//   main:   1024 blocks = 32 b-tiles x 16 l-tiles x 2 D-halves, 512 thr/block.
//           LDS 32 KB/block -> 4 blocks/CU resident = 32 waves/CU (HW max).
//           Wave w covers d-window [dh*256 + w*32, +32): stages its own window
//           (8 float4 loads, cvt_pkrtz, swizzled LDS) with NO barrier, then
//           4 steps x (8 ds_read_b128 + 128 pk ops). 8-wave LDS tree-reduce,
//           fp16 partial tile stored coalesced to d_ws (harness poisons d_ws
//           every replay anyway, so using it is free).
//   combine: min of the two fp16 partials -> f32 out, 4 MB traffic.
// LDS swizzle: d-block blk' = (blk + (row>>2)) & 3 -> compute reads are 8
// distinct rows spread over 4 bank-groups = 2-way aliasing (free per m136).

typedef _Float16 h2 __attribute__((ext_vector_type(2)));
typedef _Float16 h4 __attribute__((ext_vector_type(4)));
typedef _Float16 h8 __attribute__((ext_vector_type(8)));
typedef __fp16   fp16x2 __attribute__((ext_vector_type(2)));  // cvt_pkrtz return type

constexpr int Dv = 512;
constexpr int Lv = 512;
constexpr int Bv = 1024;

static __device__ __forceinline__ h8 max8(h8 a, h8 b) { return __builtin_elementwise_max(a, b); }
static __device__ __forceinline__ h8 min8(h8 a, h8 b) { return __builtin_elementwise_min(a, b); }
static __device__ __forceinline__ h4 min4(h4 a, h4 b) { return __builtin_elementwise_min(a, b); }
static __device__ __forceinline__ h2 min2(h2 a, h2 b) { return __builtin_elementwise_min(a, b); }

static __device__ __forceinline__ h2 pkrtz(float a, float b) {
  fp16x2 r = __builtin_amdgcn_cvt_pkrtz(a, b);
  return __builtin_bit_cast(h2, r);
}

static __device__ __forceinline__ float clip01_inv(float v) {
  // 1 - clamp(v,0,1): compiler folds clamp to v_med3_f32
  return 1.f - fminf(fmaxf(v, 0.f), 1.f);
}

__global__ __launch_bounds__(512, 4) void softand_main(
    const float* __restrict__ x, const float* __restrict__ w,
    _Float16* __restrict__ pws)   // pws[dh][b][l], two 1 MB fp16 planes
{
  // Two 32x256 fp16 planes (x-tile, c-tile), 16 KB each -> 32 KB total.
  __shared__ _Float16 smem[2 * 32 * 256] __attribute__((aligned(16)));
  _Float16* xs = smem;
  _Float16* cs = smem + 32 * 256;

  const int t    = threadIdx.x;
  const int wave = t >> 6;
  const int lane = t & 63;
  const int bid  = blockIdx.x;
  const int dh   = bid >> 9;          // [0,2) D-half
  const int bx   = (bid >> 4) & 31;   // [0,32) b-tile
  const int by   = bid & 15;          // [0,16) l-tile
  const int b0 = bx * 32, l0 = by * 32;
  const int dbase = dh * 256 + wave * 32;  // this wave's 32-d global window

  // -------- Per-wave staging: its 32-d window, all 32 rows, both operands.
  #pragma unroll
  for (int k = 0; k < 4; ++k) {
    const int row = k * 8 + (lane >> 3);
    const int dq  = lane & 7;
    const int blk  = dq >> 1;
    const int blkp = (blk + (row >> 2)) & 3;
    const int idx  = row * 256 + wave * 32 + blkp * 8 + (dq & 1) * 4;

    const float4 vx = *(const float4*)(x + (size_t)(b0 + row) * Dv + dbase + dq * 4);
    h2 p0 = pkrtz(vx.x, vx.y);
    h2 p1 = pkrtz(vx.z, vx.w);
    *(h4*)(&xs[idx]) = h4{p0.x, p0.y, p1.x, p1.y};

    const float4 vw = *(const float4*)(w + (size_t)(l0 + row) * Dv + dbase + dq * 4);
    h2 q0 = pkrtz(clip01_inv(vw.x), clip01_inv(vw.y));
    h2 q1 = pkrtz(clip01_inv(vw.z), clip01_inv(vw.w));
    *(h4*)(&cs[idx]) = h4{q0.x, q0.y, q1.x, q1.y};
  }
  // No __syncthreads: each wave reads back exactly what it wrote (wave-private
  // d-window); compiler's lgkmcnt ordering covers the wave-local LDS RAW.

  // -------- Compute: lane tile 4b x 4l, fp16x2 packs two d's
  const int bg = lane >> 3;   // [0,8) b-group (rows bg*4..bg*4+3)
  const int lg = lane & 7;    // [0,8) l-group (rows lg*4..lg*4+3)
  const int rb = bg * 4;
  const int rl = lg * 4;

  const h2 hinit = h2{(_Float16)65504.f, (_Float16)65504.f};
  h2 acc[16];
  #pragma unroll
  for (int o = 0; o < 16; ++o) acc[o] = hinit;

  #pragma unroll
  for (int s = 0; s < 4; ++s) {
    h8 xv[4], cv[4];
    #pragma unroll
    for (int i = 0; i < 4; ++i)
      xv[i] = *(const h8*)(&xs[(rb + i) * 256 + wave * 32 + (((s + bg) & 3) * 8)]);
    #pragma unroll
    for (int j = 0; j < 4; ++j)
      cv[j] = *(const h8*)(&cs[(rl + j) * 256 + wave * 32 + (((s + lg) & 3) * 8)]);
    #pragma unroll
    for (int i = 0; i < 4; ++i) {
      #pragma unroll
      for (int j = 0; j < 4; ++j) {
        const h8 t8 = max8(xv[i], cv[j]);
        const h4 lo = __builtin_shufflevector(t8, t8, 0, 1, 2, 3);
        const h4 hi = __builtin_shufflevector(t8, t8, 4, 5, 6, 7);
        const h4 m4 = min4(lo, hi);
        const h2 l2 = __builtin_shufflevector(m4, m4, 0, 1);
        const h2 h2v = __builtin_shufflevector(m4, m4, 2, 3);
        acc[i * 4 + j] = min2(acc[i * 4 + j], min2(l2, h2v));
      }
    }
  }

  // Finalize: fold d-pairs -> fin[i*2+jp] = outputs (row rb+i, cols rl+jp*2,+1)
  h2 fin[8];
  #pragma unroll
  for (int i = 0; i < 4; ++i) {
    #pragma unroll
    for (int jp = 0; jp < 2; ++jp) {
      const h2 a0 = acc[i * 4 + jp * 2];
      const h2 a1 = acc[i * 4 + jp * 2 + 1];
      const _Float16 m0 = a0.x < a0.y ? a0.x : a0.y;
      const _Float16 m1 = a1.x < a1.y ? a1.x : a1.y;
      fin[i * 2 + jp] = h2{m0, m1};
    }
  }

  // -------- Split-D tree reduction across the 8 waves (red overlays xs)
  __syncthreads();  // all waves done reading the LDS planes
  h2* red = (h2*)smem;
  for (int s = 4; s >= 1; s >>= 1) {
    if (wave >= s && wave < 2 * s) {
      #pragma unroll
      for (int k = 0; k < 8; ++k) red[((wave - s) * 8 + k) * 64 + lane] = fin[k];
    }
    __syncthreads();
    if (wave < s) {
      #pragma unroll
      for (int k = 0; k < 8; ++k)
        fin[k] = min2(fin[k], red[(wave * 8 + k) * 64 + lane]);
    }
    __syncthreads();
  }

  // -------- Publish tile, then coalesced fp16 partial store by all threads
  if (wave == 0) {
    #pragma unroll
    for (int k = 0; k < 8; ++k) red[k * 64 + lane] = fin[k];
  }
  __syncthreads();

  {
    const int b_loc = t >> 4;       // [0,32)
    const int lp    = t & 15;       // h2-column within tile
    const h2 v = red[((b_loc & 3) * 2 + (lp & 1)) * 64 + (b_loc >> 2) * 8 + (lp >> 1)];
    _Float16* dst = pws + (size_t)dh * (Bv * Lv)
                  + (size_t)(b0 + b_loc) * Lv + l0 + lp * 2;
    *(h2*)dst = v;   // 16 threads x 4B = 64B contiguous per row
  }
}

// combine: out[i] = (float)min(p0[i], p1[i]); 8 halves per thread.
__global__ __launch_bounds__(256) void softand_combine(
    const _Float16* __restrict__ pws, float* __restrict__ out)
{
  const int i = blockIdx.x * 256 + threadIdx.x;   // [0, 64K) h8-groups
  const h8 a = *(const h8*)(pws + (size_t)i * 8);
  const h8 b = *(const h8*)(pws + (size_t)(Bv * Lv) + (size_t)i * 8);
  const h8 m = min8(a, b);
  float4 o0, o1;
  o0.x = (float)m.s0; o0.y = (float)m.s1; o0.z = (float)m.s2; o0.w = (float)m.s3;
  o1.x = (float)m.s4; o1.y = (float)m.s5; o1.z = (float)m.s6; o1.w = (float)m.s7;
  float* dst = out + (size_t)i * 8;
  *(float4*)(dst + 0) = o0;
  *(float4*)(dst + 4) = o1;
}

// Fallback (workspace too small): naive exact f32.
__global__ __launch_bounds__(256) void softand_naive(
    const float* __restrict__ x, const float* __restrict__ w,
    float* __restrict__ out)
{
  const int i = blockIdx.x * 256 + threadIdx.x;
  if (i >= Bv * Lv) return;
  const int b = i >> 9;
  const int l = i & (Lv - 1);
  float m = 1e30f;
  for (int d = 0; d < Dv; ++d) {
    const float c = 1.f - fminf(fmaxf(w[(size_t)l * Dv + d], 0.f), 1.f);
    m = fminf(m, fmaxf(x[(size_t)b * Dv + d], c));
  }
  out[i] = m;
}

extern "C" void kernel_launch(void* const* d_in, const int* in_sizes, int n_in,
                              void* d_out, int out_size, void* d_ws, size_t ws_size,
                              hipStream_t stream) {
  const float* x = (const float*)d_in[0];
  const float* w = (const float*)d_in[1];
  float* out = (float*)d_out;
  (void)in_sizes; (void)n_in; (void)out_size;

  const size_t need = (size_t)2 * Bv * Lv * sizeof(_Float16);  // 2 MB partials
  if (ws_size < need) {
    softand_naive<<<(Bv * Lv + 255) / 256, 256, 0, stream>>>(x, w, out);
    return;
  }

  _Float16* pws = (_Float16*)d_ws;
  softand_main<<<1024, 512, 0, stream>>>(x, w, pws);
  softand_combine<<<(Bv * Lv / 8) / 256, 256, 0, stream>>>(pws, out);
}

// Round 6
// 68.339 us; speedup vs baseline: 1.0560x; 1.0560x over previous
//
#include <hip/hip_runtime.h>
#include <cstdint>
#include <cstddef>

// out[b,l] = min_d max(x[b,d], 1 - clip(w[l,d],0,1)),  B=1024, L=512, D=512, f32.
// Packed fp16 (v_pk_min/max_f16) tropical matmul; D packed into the fp16x2
// lanes (acc.x = even d, acc.y = odd d) so no transpose is ever needed.
//
// R6: SINGLE kernel (fewest graph nodes -- each extra node costs ~2 us of
// launch/gap overhead per R5 post-mortem), 32 KB LDS, D covered in TWO
// wave-private passes (wave w owns d-windows w*32 and 256+w*32).
// All LDS regions are wave-private -> ZERO barriers in the main loop; both
// passes unrolled so pass-1 global loads overlap pass-0 compute.
// LDS swizzle: d-block blk' = (blk + (row>>2)) & 3 keeps compute reads at
// <=2-way bank aliasing (free per m136).

typedef _Float16 h2 __attribute__((ext_vector_type(2)));
typedef _Float16 h4 __attribute__((ext_vector_type(4)));
typedef _Float16 h8 __attribute__((ext_vector_type(8)));
typedef __fp16   fp16x2 __attribute__((ext_vector_type(2)));  // cvt_pkrtz return type

constexpr int Dv = 512;
constexpr int Lv = 512;
constexpr int Bv = 1024;

static __device__ __forceinline__ h8 max8(h8 a, h8 b) { return __builtin_elementwise_max(a, b); }
static __device__ __forceinline__ h4 min4(h4 a, h4 b) { return __builtin_elementwise_min(a, b); }
static __device__ __forceinline__ h2 min2(h2 a, h2 b) { return __builtin_elementwise_min(a, b); }

static __device__ __forceinline__ h2 pkrtz(float a, float b) {
  fp16x2 r = __builtin_amdgcn_cvt_pkrtz(a, b);
  return __builtin_bit_cast(h2, r);
}

static __device__ __forceinline__ float clip01_inv(float v) {
  return 1.f - fminf(fmaxf(v, 0.f), 1.f);  // folds to v_med3 + v_sub
}

__global__ __launch_bounds__(512, 2) void softand_fused(
    const float* __restrict__ x, const float* __restrict__ w,
    float* __restrict__ out)
{
  // Two 32x256 fp16 planes (x-tile, c-tile), 16 KB each -> 32 KB total.
  __shared__ _Float16 smem[2 * 32 * 256] __attribute__((aligned(16)));
  _Float16* xs = smem;
  _Float16* cs = smem + 32 * 256;

  const int t    = threadIdx.x;
  const int wave = t >> 6;
  const int lane = t & 63;
  const int bx   = blockIdx.x >> 4;   // [0,32) b-tile
  const int by   = blockIdx.x & 15;   // [0,16) l-tile
  const int b0 = bx * 32, l0 = by * 32;

  const int bg = lane >> 3;   // [0,8) b-group (rows bg*4..bg*4+3)
  const int lg = lane & 7;    // [0,8) l-group (rows lg*4..lg*4+3)
  const int rb = bg * 4;
  const int rl = lg * 4;

  const h2 hinit = h2{(_Float16)65504.f, (_Float16)65504.f};
  h2 acc[16];
  #pragma unroll
  for (int o = 0; o < 16; ++o) acc[o] = hinit;

  // -------- Two wave-private D-passes, no barriers anywhere in here.
  #pragma unroll
  for (int p = 0; p < 2; ++p) {
    const int dbase = p * 256 + wave * 32;  // this wave's 32-d global window

    // Stage this wave's window: 32 rows x 32 d, both operands.
    #pragma unroll
    for (int k = 0; k < 4; ++k) {
      const int row = k * 8 + (lane >> 3);
      const int dq  = lane & 7;
      const int blkp = ((dq >> 1) + (row >> 2)) & 3;
      const int idx  = row * 256 + wave * 32 + blkp * 8 + (dq & 1) * 4;

      const float4 vx = *(const float4*)(x + (size_t)(b0 + row) * Dv + dbase + dq * 4);
      h2 p0 = pkrtz(vx.x, vx.y);
      h2 p1 = pkrtz(vx.z, vx.w);
      *(h4*)(&xs[idx]) = h4{p0.x, p0.y, p1.x, p1.y};

      const float4 vw = *(const float4*)(w + (size_t)(l0 + row) * Dv + dbase + dq * 4);
      h2 q0 = pkrtz(clip01_inv(vw.x), clip01_inv(vw.y));
      h2 q1 = pkrtz(clip01_inv(vw.z), clip01_inv(vw.w));
      *(h4*)(&cs[idx]) = h4{q0.x, q0.y, q1.x, q1.y};
    }
    // Wave reads back exactly what it wrote; lgkmcnt ordering covers the RAW.

    #pragma unroll
    for (int s = 0; s < 4; ++s) {
      h8 xv[4], cv[4];
      #pragma unroll
      for (int i = 0; i < 4; ++i)
        xv[i] = *(const h8*)(&xs[(rb + i) * 256 + wave * 32 + (((s + bg) & 3) * 8)]);
      #pragma unroll
      for (int j = 0; j < 4; ++j)
        cv[j] = *(const h8*)(&cs[(rl + j) * 256 + wave * 32 + (((s + lg) & 3) * 8)]);
      #pragma unroll
      for (int i = 0; i < 4; ++i) {
        #pragma unroll
        for (int j = 0; j < 4; ++j) {
          const h8 t8 = max8(xv[i], cv[j]);
          const h4 lo = __builtin_shufflevector(t8, t8, 0, 1, 2, 3);
          const h4 hi = __builtin_shufflevector(t8, t8, 4, 5, 6, 7);
          const h4 m4 = min4(lo, hi);
          const h2 l2  = __builtin_shufflevector(m4, m4, 0, 1);
          const h2 h2v = __builtin_shufflevector(m4, m4, 2, 3);
          acc[i * 4 + j] = min2(acc[i * 4 + j], min2(l2, h2v));
        }
      }
    }
  }

  // Finalize: fold d-pairs -> fin[i*2+jp] = (row rb+i, cols rl+jp*2, +1)
  h2 fin[8];
  #pragma unroll
  for (int i = 0; i < 4; ++i) {
    #pragma unroll
    for (int jp = 0; jp < 2; ++jp) {
      const h2 a0 = acc[i * 4 + jp * 2];
      const h2 a1 = acc[i * 4 + jp * 2 + 1];
      const _Float16 m0 = a0.x < a0.y ? a0.x : a0.y;
      const _Float16 m1 = a1.x < a1.y ? a1.x : a1.y;
      fin[i * 2 + jp] = h2{m0, m1};
    }
  }

  // -------- Split-D tree reduction across the 8 waves (red overlays xs)
  __syncthreads();  // all waves done with their LDS windows
  h2* red = (h2*)smem;
  for (int s = 4; s >= 1; s >>= 1) {
    if (wave >= s && wave < 2 * s) {
      #pragma unroll
      for (int k = 0; k < 8; ++k) red[((wave - s) * 8 + k) * 64 + lane] = fin[k];
    }
    __syncthreads();
    if (wave < s) {
      #pragma unroll
      for (int k = 0; k < 8; ++k)
        fin[k] = min2(fin[k], red[(wave * 8 + k) * 64 + lane]);
    }
    __syncthreads();
  }

  // -------- Publish tile, then coalesced f32 store by all 512 threads
  if (wave == 0) {
    #pragma unroll
    for (int k = 0; k < 8; ++k) red[k * 64 + lane] = fin[k];
  }
  __syncthreads();

  {
    const int b_loc = t >> 4;       // [0,32)
    const int lp    = t & 15;       // h2-column within tile
    // slot k = i*2+jp with i = b_loc&3, jp = lp&1; lane_src = (b_loc>>2)*8 + (lp>>1)
    const h2 v = red[((b_loc & 3) * 2 + (lp & 1)) * 64 + (b_loc >> 2) * 8 + (lp >> 1)];
    float2 o;
    o.x = (float)v.x;
    o.y = (float)v.y;
    *(float2*)(out + (size_t)(b0 + b_loc) * Lv + l0 + lp * 2) = o;
  }
}

extern "C" void kernel_launch(void* const* d_in, const int* in_sizes, int n_in,
                              void* d_out, int out_size, void* d_ws, size_t ws_size,
                              hipStream_t stream) {
  const float* x = (const float*)d_in[0];
  const float* w = (const float*)d_in[1];
  float* out = (float*)d_out;
  (void)d_ws; (void)ws_size; (void)in_sizes; (void)n_in; (void)out_size;

  softand_fused<<<512, 512, 0, stream>>>(x, w, out);
}